// Round 5
// baseline (250.932 us; speedup 1.0000x reference)
//
#include <hip/hip_runtime.h>
#include <hip/hip_bf16.h>

#define NN 50000
#define NE 800000
#define KD 768
#define HIDD 128
#define NC 6

typedef __attribute__((ext_vector_type(8))) short bf16x8;
typedef __attribute__((ext_vector_type(4))) float f32x4;

__device__ __forceinline__ ushort f2bf(float f) {
    union { float f; unsigned u; } v; v.f = f;
    unsigned u = v.u + 0x7FFF + ((v.u >> 16) & 1);   // round-to-nearest-even
    return (ushort)(u >> 16);
}
__device__ __forceinline__ float bf2f(ushort h) {
    union { unsigned u; float f; } v; v.u = ((unsigned)h) << 16;
    return v.f;
}
__device__ __forceinline__ void gll16(const void* g, void* l) {
    __builtin_amdgcn_global_load_lds((const __attribute__((address_space(1))) void*)g,
                                     (__attribute__((address_space(3))) void*)l, 16, 0, 0);
}

// ---------------- weight prep granule (packed, gll-ready, swizzle baked in) ----------------

template <int KTOT>
__device__ __forceinline__ void pack_granule(const float* __restrict__ W,
                                             ushort* __restrict__ WTp, int gi) {
    const int KS = KTOT / 64;
    int ci = gi / (KS * 64);
    int rem = gi % (KS * 64);
    int ks = rem >> 6;
    int lane = rem & 63;
    int lr = lane >> 3;
    int lg = (lane & 7) ^ lr;
    int c = ci * 8 + lr;
    ushort tmp[8];
#pragma unroll
    for (int j = 0; j < 8; ++j)
        tmp[j] = f2bf(W[(size_t)(ks * 64 + lg * 8 + j) * HIDD + c]);
    *(bf16x8*)&WTp[(size_t)gi * 8] = *(bf16x8*)tmp;
}

// ---------------- fused: edge count (atomics) + weight pack ----------------
// blocks [0,3125): count; blocks [3125,3181): pack granules (12288 + 2048).

__global__ void count_prep_kernel(const int* __restrict__ ei, int* __restrict__ cnt,
                                  const float* __restrict__ W1, const float* __restrict__ W2,
                                  ushort* __restrict__ WT1p, ushort* __restrict__ WT2p) {
    const int CB = NE / 256;                // 3125
    const int G1 = 16 * (KD / 64) * 64;     // 12288
    const int G2 = 16 * (HIDD / 64) * 64;   // 2048
    int b = blockIdx.x;
    if (b < CB) {
        int e = b * 256 + threadIdx.x;
        int d = ei[NE + e];
        d = min(max(d, 0), NN - 1);
        atomicAdd(&cnt[d], 1);
    } else {
        int gi = (b - CB) * 256 + threadIdx.x;
        if (gi < G1) pack_granule<KD>(W1, WT1p, gi);
        else if (gi < G1 + G2) pack_granule<HIDD>(W2, WT2p, gi - G1);
    }
}

// ---------------- CSR scan ----------------

__global__ void scan_blocks_kernel(const int* __restrict__ cnt, int* __restrict__ row_ptr,
                                   float* __restrict__ dinv, int* __restrict__ bsum) {
    __shared__ int s[256];
    int t = threadIdx.x;
    int base = blockIdx.x * 1024 + t * 4;
    int v[4];
    int sum = 0;
#pragma unroll
    for (int j = 0; j < 4; ++j) {
        int i = base + j;
        v[j] = (i < NN) ? cnt[i] : 0;
        sum += v[j];
    }
    s[t] = sum;
    __syncthreads();
    for (int off = 1; off < 256; off <<= 1) {
        int val = (t >= off) ? s[t - off] : 0;
        __syncthreads();
        s[t] += val;
        __syncthreads();
    }
    int excl = s[t] - sum;
    if (t == 0) bsum[blockIdx.x] = s[255];
    int run = excl;
#pragma unroll
    for (int j = 0; j < 4; ++j) {
        int i = base + j;
        if (i < NN) {
            row_ptr[i] = run;
            dinv[i] = rsqrtf((float)(v[j] + 1));
            run += v[j];
        }
    }
}

// merged: adds block offsets (derived by direct summation of <=48 bsum totals)
__global__ void scan_add_kernel(int* __restrict__ row_ptr, int* __restrict__ cursor,
                                const int* __restrict__ bsum) {
    int i = blockIdx.x * blockDim.x + threadIdx.x;
    if (i >= NN) return;
    int chunk = i >> 10;
    int off = 0;
    for (int k = 0; k < chunk; ++k) off += bsum[k];
    int r = row_ptr[i] + off;
    row_ptr[i] = r;
    cursor[i] = r;
    if (i == 0) {
        int tot = 0;
        for (int k = 0; k < 49; ++k) tot += bsum[k];
        row_ptr[NN] = tot;
    }
}

__global__ void fill_kernel(const int* __restrict__ ei, int* __restrict__ cursor,
                            int* __restrict__ col) {
    int e = blockIdx.x * blockDim.x + threadIdx.x;
    if (e >= NE) return;
    int sidx = ei[e];
    int d = ei[NE + e];
    sidx = min(max(sidx, 0), NN - 1);
    d = min(max(d, 0), NN - 1);
    int pos = atomicAdd(&cursor[d], 1);
    col[pos] = sidx;
}

// ---------------- MFMA GEMM1: hs1[r][c] = bf16(dinv[r] * sum_k x[r][k] W1[k][c]) ----------------
// BM=32, BN=128, BK=64. 4 waves (2x2), wave tile 16x64. fp32 A converted in staging.

__global__ __launch_bounds__(256) void mfma_gemm1(const float* __restrict__ A,
                                                  const ushort* __restrict__ WTp,
                                                  const float* __restrict__ dinv,
                                                  ushort* __restrict__ out, int M) {
    const int KS = KD / 64;
    __shared__ ushort As[32 * 64];
    __shared__ ushort Bs[128 * 64];
    int t = threadIdx.x;
    int lane = t & 63;
    int wid = t >> 6;
    int wr = wid >> 1, wc = wid & 1;
    int row0 = blockIdx.x * 32;
    f32x4 acc[4] = {};

    for (int ks = 0; ks < KS; ++ks) {
        int k0 = ks * 64;
#pragma unroll
        for (int it = 0; it < 2; ++it) {
            int r = (t >> 4) + it * 16;
            int k4 = t & 15;
            int gr = min(row0 + r, M - 1);
            float4 v = *(const float4*)&A[(size_t)gr * KD + k0 + k4 * 4];
            ushort4 w;
            w.x = f2bf(v.x); w.y = f2bf(v.y); w.z = f2bf(v.z); w.w = f2bf(v.w);
            int g = k4 >> 1, half = k4 & 1;
            *(ushort4*)&As[r * 64 + ((g ^ (r & 7)) * 8) + half * 4] = w;
        }
#pragma unroll
        for (int it = 0; it < 4; ++it) {
            int ci = wid * 4 + it;
            gll16(&WTp[(size_t)((ci * KS + ks) * 64 + lane) * 8], &Bs[ci * 512]);
        }
        __syncthreads();
#pragma unroll
        for (int h = 0; h < 2; ++h) {
            int q = h * 4 + (lane >> 4);
            int r = wr * 16 + (lane & 15);
            bf16x8 a = *(const bf16x8*)&As[r * 64 + (q ^ (r & 7)) * 8];
#pragma unroll
            for (int n = 0; n < 4; ++n) {
                int c = wc * 64 + n * 16 + (lane & 15);
                bf16x8 b = *(const bf16x8*)&Bs[c * 64 + (q ^ (c & 7)) * 8];
                acc[n] = __builtin_amdgcn_mfma_f32_16x16x32_bf16(a, b, acc[n], 0, 0, 0);
            }
        }
        __syncthreads();
    }
#pragma unroll
    for (int reg = 0; reg < 4; ++reg) {
        int row = row0 + wr * 16 + (lane >> 4) * 4 + reg;
        if (row < M) {
            float d = dinv[row];
#pragma unroll
            for (int n = 0; n < 4; ++n) {
                int colg = wc * 64 + n * 16 + (lane & 15);
                out[(size_t)row * 128 + colg] = f2bf(acc[n][reg] * d);
            }
        }
    }
}

// ---------------- CSR aggregation (bf16 in/out, fp32 accum), one wave/node ----------------
// MODE 0: out = bf16( dinv * relu(dinv*sum + bias) )   [h1s, pre-scaled for layer 2]
// MODE 1: out = bf16( dinv * sum )                      [g]

__device__ __forceinline__ void acc_edge(float& ax, float& ay, unsigned w) {
    ax += bf2f((ushort)(w & 0xffff));
    ay += bf2f((ushort)(w >> 16));
}

template <int MODE>
__global__ void agg_kernel(const ushort* __restrict__ hs, const int* __restrict__ row_ptr,
                           const int* __restrict__ col, const float* __restrict__ dinv,
                           const float* __restrict__ bias, ushort* __restrict__ out) {
    int wv = threadIdx.x >> 6;
    int l = threadIdx.x & 63;
    int i = blockIdx.x * 4 + wv;
    unsigned v0 = *(const unsigned*)&hs[(size_t)i * 128 + 2 * l];
    float ax = bf2f((ushort)(v0 & 0xffff));
    float ay = bf2f((ushort)(v0 >> 16));
    int e0 = row_ptr[i], e1 = row_ptr[i + 1];
    int e = e0;
    for (; e + 8 <= e1; e += 8) {
        unsigned w[8];
#pragma unroll
        for (int u = 0; u < 8; ++u)
            w[u] = *(const unsigned*)&hs[(size_t)col[e + u] * 128 + 2 * l];
#pragma unroll
        for (int u = 0; u < 8; ++u) acc_edge(ax, ay, w[u]);
    }
    for (; e + 4 <= e1; e += 4) {
        unsigned w[4];
#pragma unroll
        for (int u = 0; u < 4; ++u)
            w[u] = *(const unsigned*)&hs[(size_t)col[e + u] * 128 + 2 * l];
#pragma unroll
        for (int u = 0; u < 4; ++u) acc_edge(ax, ay, w[u]);
    }
    for (; e < e1; ++e)
        acc_edge(ax, ay, *(const unsigned*)&hs[(size_t)col[e] * 128 + 2 * l]);
    float d = dinv[i];
    float ox, oy;
    if (MODE == 0) {
        ox = d * fmaxf(fmaf(ax, d, bias[2 * l]), 0.f);
        oy = d * fmaxf(fmaf(ay, d, bias[2 * l + 1]), 0.f);
    } else {
        ox = ax * d;
        oy = ay * d;
    }
    unsigned o = (unsigned)f2bf(ox) | ((unsigned)f2bf(oy) << 16);
    *(unsigned*)&out[(size_t)i * 128 + 2 * l] = o;
}

// ---------------- fused GEMM2 + heads ----------------
// h2 = relu(g @ W2 + b2) kept in LDS (fp32); then per-row heads + log_softmax.

__global__ __launch_bounds__(256) void gemm2_heads_kernel(
    const ushort* __restrict__ g, const ushort* __restrict__ WTp,
    const float* __restrict__ b2,
    const float* __restrict__ Wi, const float* __restrict__ bi,
    const float* __restrict__ Wl, const float* __restrict__ bl,
    float* __restrict__ out, int M) {
    const int KS = HIDD / 64;   // 2
    __shared__ ushort As[32 * 64];
    __shared__ ushort Bs[128 * 64];
    __shared__ float h2s[32][130];
    int t = threadIdx.x;
    int lane = t & 63;
    int wid = t >> 6;
    int wr = wid >> 1, wc = wid & 1;
    int row0 = blockIdx.x * 32;
    f32x4 acc[4] = {};

    int lr = lane >> 3;
    int lg = (lane & 7) ^ lr;

    for (int ks = 0; ks < KS; ++ks) {
        int k0 = ks * 64;
        {
            int r = wid * 8 + lr;
            int gr = min(row0 + r, M - 1);
            gll16(&g[(size_t)gr * HIDD + k0 + lg * 8], &As[wid * 8 * 64]);
        }
#pragma unroll
        for (int it = 0; it < 4; ++it) {
            int ci = wid * 4 + it;
            gll16(&WTp[(size_t)((ci * KS + ks) * 64 + lane) * 8], &Bs[ci * 512]);
        }
        __syncthreads();
#pragma unroll
        for (int h = 0; h < 2; ++h) {
            int q = h * 4 + (lane >> 4);
            int r = wr * 16 + (lane & 15);
            bf16x8 a = *(const bf16x8*)&As[r * 64 + (q ^ (r & 7)) * 8];
#pragma unroll
            for (int n = 0; n < 4; ++n) {
                int c = wc * 64 + n * 16 + (lane & 15);
                bf16x8 b = *(const bf16x8*)&Bs[c * 64 + (q ^ (c & 7)) * 8];
                acc[n] = __builtin_amdgcn_mfma_f32_16x16x32_bf16(a, b, acc[n], 0, 0, 0);
            }
        }
        __syncthreads();
    }
    // h2 = relu(acc + b2) -> LDS (fp32, never rounded)
#pragma unroll
    for (int n = 0; n < 4; ++n) {
        int colg = wc * 64 + n * 16 + (lane & 15);
        float bb = b2[colg];
#pragma unroll
        for (int reg = 0; reg < 4; ++reg) {
            int r = wr * 16 + (lane >> 4) * 4 + reg;
            h2s[r][colg] = fmaxf(acc[n][reg] + bb, 0.f);
        }
    }
    __syncthreads();

    // heads: wave wid handles rows wid*8 .. wid*8+7
    int l = lane;
    float4 wi0 = *(const float4*)&Wi[l * 12];
    float4 wi1 = *(const float4*)&Wi[l * 12 + 4];
    float4 wi2 = *(const float4*)&Wi[l * 12 + 8];
    float4 wl0 = *(const float4*)&Wl[l * 12];
    float4 wl1 = *(const float4*)&Wl[l * 12 + 4];
    float4 wl2 = *(const float4*)&Wl[l * 12 + 8];
    float bia[6], bla[6];
#pragma unroll
    for (int c = 0; c < 6; ++c) { bia[c] = bi[c]; bla[c] = bl[c]; }

    for (int rr = 0; rr < 8; ++rr) {
        int r = wid * 8 + rr;
        int i = row0 + r;
        if (i >= M) break;
        float ox = h2s[r][2 * l];
        float oy = h2s[r][2 * l + 1];
        float pi[6], pl[6];
        pi[0] = ox * wi0.x + oy * wi1.z;
        pi[1] = ox * wi0.y + oy * wi1.w;
        pi[2] = ox * wi0.z + oy * wi2.x;
        pi[3] = ox * wi0.w + oy * wi2.y;
        pi[4] = ox * wi1.x + oy * wi2.z;
        pi[5] = ox * wi1.y + oy * wi2.w;
        pl[0] = ox * wl0.x + oy * wl1.z;
        pl[1] = ox * wl0.y + oy * wl1.w;
        pl[2] = ox * wl0.z + oy * wl2.x;
        pl[3] = ox * wl0.w + oy * wl2.y;
        pl[4] = ox * wl1.x + oy * wl2.z;
        pl[5] = ox * wl1.y + oy * wl2.w;
#pragma unroll
        for (int off = 1; off < 64; off <<= 1) {
#pragma unroll
            for (int c = 0; c < 6; ++c) {
                pi[c] += __shfl_xor(pi[c], off);
                pl[c] += __shfl_xor(pl[c], off);
            }
        }
#pragma unroll
        for (int c = 0; c < 6; ++c) {
            pi[c] += bia[c];
            pl[c] += bla[c];
        }
        float mi = fmaxf(fmaxf(fmaxf(pi[0], pi[1]), fmaxf(pi[2], pi[3])), fmaxf(pi[4], pi[5]));
        float ml = fmaxf(fmaxf(fmaxf(pl[0], pl[1]), fmaxf(pl[2], pl[3])), fmaxf(pl[4], pl[5]));
        float si = 0.f, sl = 0.f;
#pragma unroll
        for (int c = 0; c < 6; ++c) {
            si += expf(pi[c] - mi);
            sl += expf(pl[c] - ml);
        }
        float lsi = mi + logf(si), lsl = ml + logf(sl);
#pragma unroll
        for (int c = 0; c < 6; ++c) {
            if (l == c)     out[(size_t)i * NC + c] = pi[c] - lsi;
            if (l == 6 + c) out[(size_t)NN * NC + (size_t)i * NC + c] = pl[c] - lsl;
        }
    }
}

extern "C" void kernel_launch(void* const* d_in, const int* in_sizes, int n_in,
                              void* d_out, int out_size, void* d_ws, size_t ws_size,
                              hipStream_t stream) {
    const float* x  = (const float*)d_in[0];
    const int*   ei = (const int*)d_in[1];
    const float* W1 = (const float*)d_in[2];
    const float* b1 = (const float*)d_in[3];
    const float* W2 = (const float*)d_in[4];
    const float* b2 = (const float*)d_in[5];
    const float* Wi = (const float*)d_in[6];
    const float* bi = (const float*)d_in[7];
    const float* Wl = (const float*)d_in[8];
    const float* bl = (const float*)d_in[9];
    float* out = (float*)d_out;

    uint8_t* p = (uint8_t*)d_ws;
    auto alloc = [&](size_t bytes) {
        void* r = (void*)p;
        p += (bytes + 255) / 256 * 256;
        return r;
    };
    int* row_ptr = (int*)alloc((NN + 1) * sizeof(int));
    int* cursor  = (int*)alloc(NN * sizeof(int));
    int* col     = (int*)alloc(NE * sizeof(int));
    int* bsum    = (int*)alloc(64 * sizeof(int));
    float* dinv  = (float*)alloc(NN * sizeof(float));
    ushort* WT1p = (ushort*)alloc((size_t)KD * HIDD * sizeof(ushort));
    ushort* WT2p = (ushort*)alloc((size_t)HIDD * HIDD * sizeof(ushort));
    ushort* bufA = (ushort*)alloc((size_t)NN * HIDD * sizeof(ushort));
    ushort* bufB = (ushort*)alloc((size_t)NN * HIDD * sizeof(ushort));

    const int CB = NE / 256;   // 3125
    const int PB = 56;         // pack blocks

    hipMemsetAsync(cursor, 0, NN * sizeof(int), stream);
    count_prep_kernel<<<CB + PB, 256, 0, stream>>>(ei, cursor, W1, W2, WT1p, WT2p);
    scan_blocks_kernel<<<49, 256, 0, stream>>>(cursor, row_ptr, dinv, bsum);
    scan_add_kernel<<<(NN + 255) / 256, 256, 0, stream>>>(row_ptr, cursor, bsum);
    fill_kernel<<<CB, 256, 0, stream>>>(ei, cursor, col);

    const int grid = (NN + 31) / 32;
    // layer 1: hs1 = bf16(dinv*(x@W1)) ; h1s = bf16(dinv*relu(dinv*gather + b1))
    mfma_gemm1<<<grid, 256, 0, stream>>>(x, WT1p, dinv, bufA, NN);
    agg_kernel<0><<<NN / 4, 256, 0, stream>>>(bufA, row_ptr, col, dinv, b1, bufB);
    // layer 2 (commuted): g = bf16(dinv*gather(h1s)) ; h2 = relu(g@W2+b2) fused with heads
    agg_kernel<1><<<NN / 4, 256, 0, stream>>>(bufB, row_ptr, col, dinv, b1, bufA);
    gemm2_heads_kernel<<<grid, 256, 0, stream>>>(bufA, WT2p, b2, Wi, bi, Wl, bl, out, NN);
}

// Round 6
// 227.889 us; speedup vs baseline: 1.1011x; 1.1011x over previous
//
#include <hip/hip_runtime.h>
#include <hip/hip_bf16.h>

#define NN 50000
#define NE 800000
#define KD 768
#define HIDD 128
#define NC 6

typedef __attribute__((ext_vector_type(8))) short bf16x8;
typedef __attribute__((ext_vector_type(4))) float f32x4;

__device__ __forceinline__ ushort f2bf(float f) {
    union { float f; unsigned u; } v; v.f = f;
    unsigned u = v.u + 0x7FFF + ((v.u >> 16) & 1);   // round-to-nearest-even
    return (ushort)(u >> 16);
}
__device__ __forceinline__ float bf2f(ushort h) {
    union { unsigned u; float f; } v; v.u = ((unsigned)h) << 16;
    return v.f;
}
__device__ __forceinline__ void gll16(const void* g, void* l) {
    __builtin_amdgcn_global_load_lds((const __attribute__((address_space(1))) void*)g,
                                     (__attribute__((address_space(3))) void*)l, 16, 0, 0);
}

// ---------------- weight prep granule (packed, gll-ready, swizzle baked in) ----------------

template <int KTOT>
__device__ __forceinline__ void pack_granule(const float* __restrict__ W,
                                             ushort* __restrict__ WTp, int gi) {
    const int KS = KTOT / 64;
    int ci = gi / (KS * 64);
    int rem = gi % (KS * 64);
    int ks = rem >> 6;
    int lane = rem & 63;
    int lr = lane >> 3;
    int lg = (lane & 7) ^ lr;
    int c = ci * 8 + lr;
    ushort tmp[8];
#pragma unroll
    for (int j = 0; j < 8; ++j)
        tmp[j] = f2bf(W[(size_t)(ks * 64 + lg * 8 + j) * HIDD + c]);
    *(bf16x8*)&WTp[(size_t)gi * 8] = *(bf16x8*)tmp;
}

// ---------------- fused: edge count (atomics) + weight pack ----------------

__global__ void count_prep_kernel(const int* __restrict__ ei, int* __restrict__ cnt,
                                  const float* __restrict__ W1, const float* __restrict__ W2,
                                  ushort* __restrict__ WT1p, ushort* __restrict__ WT2p) {
    const int CB = NE / 256;                // 3125
    const int G1 = 16 * (KD / 64) * 64;     // 12288
    const int G2 = 16 * (HIDD / 64) * 64;   // 2048
    int b = blockIdx.x;
    if (b < CB) {
        int e = b * 256 + threadIdx.x;
        int d = ei[NE + e];
        d = min(max(d, 0), NN - 1);
        atomicAdd(&cnt[d], 1);
    } else {
        int gi = (b - CB) * 256 + threadIdx.x;
        if (gi < G1) pack_granule<KD>(W1, WT1p, gi);
        else if (gi < G1 + G2) pack_granule<HIDD>(W2, WT2p, gi - G1);
    }
}

// ---------------- CSR scan ----------------

__global__ void scan_blocks_kernel(const int* __restrict__ cnt, int* __restrict__ row_ptr,
                                   float* __restrict__ dinv, int* __restrict__ bsum) {
    __shared__ int s[256];
    int t = threadIdx.x;
    int base = blockIdx.x * 1024 + t * 4;
    int v[4];
    int sum = 0;
#pragma unroll
    for (int j = 0; j < 4; ++j) {
        int i = base + j;
        v[j] = (i < NN) ? cnt[i] : 0;
        sum += v[j];
    }
    s[t] = sum;
    __syncthreads();
    for (int off = 1; off < 256; off <<= 1) {
        int val = (t >= off) ? s[t - off] : 0;
        __syncthreads();
        s[t] += val;
        __syncthreads();
    }
    int excl = s[t] - sum;
    if (t == 0) bsum[blockIdx.x] = s[255];
    int run = excl;
#pragma unroll
    for (int j = 0; j < 4; ++j) {
        int i = base + j;
        if (i < NN) {
            row_ptr[i] = run;
            dinv[i] = rsqrtf((float)(v[j] + 1));
            run += v[j];
        }
    }
}

// adds block offsets (derived by direct summation of <=48 bsum totals)
__global__ void scan_add_kernel(int* __restrict__ row_ptr, int* __restrict__ cursor,
                                const int* __restrict__ bsum) {
    int i = blockIdx.x * blockDim.x + threadIdx.x;
    if (i >= NN) return;
    int chunk = i >> 10;
    int off = 0;
    for (int k = 0; k < chunk; ++k) off += bsum[k];
    int r = row_ptr[i] + off;
    row_ptr[i] = r;
    cursor[i] = r;
    if (i == 0) {
        int tot = 0;
        for (int k = 0; k < 49; ++k) tot += bsum[k];
        row_ptr[NN] = tot;
    }
}

__global__ void fill_kernel(const int* __restrict__ ei, int* __restrict__ cursor,
                            int* __restrict__ col) {
    int e = blockIdx.x * blockDim.x + threadIdx.x;
    if (e >= NE) return;
    int sidx = ei[e];
    int d = ei[NE + e];
    sidx = min(max(sidx, 0), NN - 1);
    d = min(max(d, 0), NN - 1);
    int pos = atomicAdd(&cursor[d], 1);
    col[pos] = sidx;
}

// ---------------- MFMA GEMM1: hs1[r][c] = bf16(dinv[r] * sum_k x[r][k] W1[k][c]) ----------------
// BM=64, BN=128, BK=64. 782 blocks, 4 waves (2x2), wave tile 32x64 = 2x4 frags.

__global__ __launch_bounds__(256) void mfma_gemm1(const float* __restrict__ A,
                                                  const ushort* __restrict__ WTp,
                                                  const float* __restrict__ dinv,
                                                  ushort* __restrict__ out, int M) {
    const int KS = KD / 64;
    __shared__ ushort As[64 * 64];
    __shared__ ushort Bs[128 * 64];
    int t = threadIdx.x;
    int lane = t & 63;
    int wid = t >> 6;
    int wr = wid >> 1, wc = wid & 1;
    int row0 = blockIdx.x * 64;
    f32x4 acc[2][4] = {};

    for (int ks = 0; ks < KS; ++ks) {
        int k0 = ks * 64;
#pragma unroll
        for (int it = 0; it < 4; ++it) {
            int r = (t >> 4) + it * 16;
            int k4 = t & 15;
            int gr = min(row0 + r, M - 1);
            float4 v = *(const float4*)&A[(size_t)gr * KD + k0 + k4 * 4];
            ushort4 w;
            w.x = f2bf(v.x); w.y = f2bf(v.y); w.z = f2bf(v.z); w.w = f2bf(v.w);
            int g = k4 >> 1, half = k4 & 1;
            *(ushort4*)&As[r * 64 + ((g ^ (r & 7)) * 8) + half * 4] = w;
        }
#pragma unroll
        for (int it = 0; it < 4; ++it) {
            int ci = wid * 4 + it;
            gll16(&WTp[(size_t)((ci * KS + ks) * 64 + lane) * 8], &Bs[ci * 512]);
        }
        __syncthreads();
#pragma unroll
        for (int h = 0; h < 2; ++h) {
            int q = h * 4 + (lane >> 4);
            bf16x8 a[2];
#pragma unroll
            for (int m = 0; m < 2; ++m) {
                int r = wr * 32 + m * 16 + (lane & 15);
                a[m] = *(const bf16x8*)&As[r * 64 + (q ^ (r & 7)) * 8];
            }
#pragma unroll
            for (int n = 0; n < 4; ++n) {
                int c = wc * 64 + n * 16 + (lane & 15);
                bf16x8 b = *(const bf16x8*)&Bs[c * 64 + (q ^ (c & 7)) * 8];
#pragma unroll
                for (int m = 0; m < 2; ++m)
                    acc[m][n] = __builtin_amdgcn_mfma_f32_16x16x32_bf16(a[m], b, acc[m][n], 0, 0, 0);
            }
        }
        __syncthreads();
    }
#pragma unroll
    for (int m = 0; m < 2; ++m) {
#pragma unroll
        for (int reg = 0; reg < 4; ++reg) {
            int row = row0 + wr * 32 + m * 16 + (lane >> 4) * 4 + reg;
            if (row < M) {
                float d = dinv[row];
#pragma unroll
                for (int n = 0; n < 4; ++n) {
                    int colg = wc * 64 + n * 16 + (lane & 15);
                    out[(size_t)row * 128 + colg] = f2bf(acc[m][n][reg] * d);
                }
            }
        }
    }
}

// ---------------- MFMA GEMM2: hs2[r][c] = bf16(dinv[r] * sum_k h1[r][k] W2[k][c]) ----------------
// BM=64, bf16 A staged via gll (pre-swizzled source).

__global__ __launch_bounds__(256) void mfma_gemm2(const ushort* __restrict__ A,
                                                  const ushort* __restrict__ WTp,
                                                  const float* __restrict__ dinv,
                                                  ushort* __restrict__ out, int M) {
    const int KS = HIDD / 64;   // 2
    __shared__ ushort As[64 * 64];
    __shared__ ushort Bs[128 * 64];
    int t = threadIdx.x;
    int lane = t & 63;
    int wid = t >> 6;
    int wr = wid >> 1, wc = wid & 1;
    int row0 = blockIdx.x * 64;
    f32x4 acc[2][4] = {};

    int lr = lane >> 3;
    int lg = (lane & 7) ^ lr;

    for (int ks = 0; ks < KS; ++ks) {
        int k0 = ks * 64;
#pragma unroll
        for (int it = 0; it < 2; ++it) {
            int ci2 = wid * 2 + it;
            int r = ci2 * 8 + lr;
            int gr = min(row0 + r, M - 1);
            gll16(&A[(size_t)gr * HIDD + k0 + lg * 8], &As[ci2 * 512]);
        }
#pragma unroll
        for (int it = 0; it < 4; ++it) {
            int ci = wid * 4 + it;
            gll16(&WTp[(size_t)((ci * KS + ks) * 64 + lane) * 8], &Bs[ci * 512]);
        }
        __syncthreads();
#pragma unroll
        for (int h = 0; h < 2; ++h) {
            int q = h * 4 + (lane >> 4);
            bf16x8 a[2];
#pragma unroll
            for (int m = 0; m < 2; ++m) {
                int r = wr * 32 + m * 16 + (lane & 15);
                a[m] = *(const bf16x8*)&As[r * 64 + (q ^ (r & 7)) * 8];
            }
#pragma unroll
            for (int n = 0; n < 4; ++n) {
                int c = wc * 64 + n * 16 + (lane & 15);
                bf16x8 b = *(const bf16x8*)&Bs[c * 64 + (q ^ (c & 7)) * 8];
#pragma unroll
                for (int m = 0; m < 2; ++m)
                    acc[m][n] = __builtin_amdgcn_mfma_f32_16x16x32_bf16(a[m], b, acc[m][n], 0, 0, 0);
            }
        }
        __syncthreads();
    }
#pragma unroll
    for (int m = 0; m < 2; ++m) {
#pragma unroll
        for (int reg = 0; reg < 4; ++reg) {
            int row = row0 + wr * 32 + m * 16 + (lane >> 4) * 4 + reg;
            if (row < M) {
                float d = dinv[row];
#pragma unroll
                for (int n = 0; n < 4; ++n) {
                    int colg = wc * 64 + n * 16 + (lane & 15);
                    out[(size_t)row * 128 + colg] = f2bf(acc[m][n][reg] * d);
                }
            }
        }
    }
}

// ---------------- CSR aggregation (bf16 in/out, fp32 accum), tiered 16/8/4/1 gather ----------------

__device__ __forceinline__ void acc_edge(float& ax, float& ay, unsigned w) {
    ax += bf2f((ushort)(w & 0xffff));
    ay += bf2f((ushort)(w >> 16));
}

template <int U>
__device__ __forceinline__ int gather_tier(const ushort* __restrict__ hs,
                                           const int* __restrict__ col,
                                           int e, int e1, int l, float& ax, float& ay) {
    for (; e + U <= e1; e += U) {
        unsigned w[U];
#pragma unroll
        for (int u = 0; u < U; ++u)
            w[u] = *(const unsigned*)&hs[(size_t)col[e + u] * 128 + 2 * l];
#pragma unroll
        for (int u = 0; u < U; ++u) acc_edge(ax, ay, w[u]);
    }
    return e;
}

// agg1: h1 = bf16(relu(dinv*sum + b1))
__global__ void agg1_kernel(const ushort* __restrict__ hs, const int* __restrict__ row_ptr,
                            const int* __restrict__ col, const float* __restrict__ dinv,
                            const float* __restrict__ bias, ushort* __restrict__ out) {
    int wv = threadIdx.x >> 6;
    int l = threadIdx.x & 63;
    int i = blockIdx.x * 4 + wv;
    unsigned v0 = *(const unsigned*)&hs[(size_t)i * 128 + 2 * l];
    float ax = bf2f((ushort)(v0 & 0xffff));
    float ay = bf2f((ushort)(v0 >> 16));
    int e0 = row_ptr[i], e1 = row_ptr[i + 1];
    int e = e0;
    e = gather_tier<16>(hs, col, e, e1, l, ax, ay);
    e = gather_tier<8>(hs, col, e, e1, l, ax, ay);
    e = gather_tier<4>(hs, col, e, e1, l, ax, ay);
    for (; e < e1; ++e)
        acc_edge(ax, ay, *(const unsigned*)&hs[(size_t)col[e] * 128 + 2 * l]);
    float d = dinv[i];
    float ox = fmaxf(fmaf(ax, d, bias[2 * l]), 0.f);
    float oy = fmaxf(fmaf(ay, d, bias[2 * l + 1]), 0.f);
    unsigned o = (unsigned)f2bf(ox) | ((unsigned)f2bf(oy) << 16);
    *(unsigned*)&out[(size_t)i * 128 + 2 * l] = o;
}

// ---------------- fused agg2 + heads (heads hide under gather latency) ----------------

__global__ void agg2_heads_kernel(const ushort* __restrict__ hs, const int* __restrict__ row_ptr,
                                  const int* __restrict__ col, const float* __restrict__ dinv,
                                  const float* __restrict__ bias,
                                  const float* __restrict__ Wi, const float* __restrict__ bi,
                                  const float* __restrict__ Wl, const float* __restrict__ bl,
                                  float* __restrict__ out) {
    int wv = threadIdx.x >> 6;
    int l = threadIdx.x & 63;
    int i = blockIdx.x * 4 + wv;
    unsigned v0 = *(const unsigned*)&hs[(size_t)i * 128 + 2 * l];
    float ax = bf2f((ushort)(v0 & 0xffff));
    float ay = bf2f((ushort)(v0 >> 16));
    int e0 = row_ptr[i], e1 = row_ptr[i + 1];
    int e = e0;
    e = gather_tier<16>(hs, col, e, e1, l, ax, ay);
    e = gather_tier<8>(hs, col, e, e1, l, ax, ay);
    e = gather_tier<4>(hs, col, e, e1, l, ax, ay);
    for (; e < e1; ++e)
        acc_edge(ax, ay, *(const unsigned*)&hs[(size_t)col[e] * 128 + 2 * l]);
    float d = dinv[i];
    float ox = fmaxf(fmaf(ax, d, bias[2 * l]), 0.f);
    float oy = fmaxf(fmaf(ay, d, bias[2 * l + 1]), 0.f);

    // logits: lane l holds h2[2l], h2[2l+1]; Wi/Wl are [128][6] row-major
    float4 u0 = *(const float4*)&Wi[l * 12];
    float4 u1 = *(const float4*)&Wi[l * 12 + 4];
    float4 u2 = *(const float4*)&Wi[l * 12 + 8];
    float pi[6];
    pi[0] = ox * u0.x + oy * u1.z;
    pi[1] = ox * u0.y + oy * u1.w;
    pi[2] = ox * u0.z + oy * u2.x;
    pi[3] = ox * u0.w + oy * u2.y;
    pi[4] = ox * u1.x + oy * u2.z;
    pi[5] = ox * u1.y + oy * u2.w;
    u0 = *(const float4*)&Wl[l * 12];
    u1 = *(const float4*)&Wl[l * 12 + 4];
    u2 = *(const float4*)&Wl[l * 12 + 8];
    float pl[6];
    pl[0] = ox * u0.x + oy * u1.z;
    pl[1] = ox * u0.y + oy * u1.w;
    pl[2] = ox * u0.z + oy * u2.x;
    pl[3] = ox * u0.w + oy * u2.y;
    pl[4] = ox * u1.x + oy * u2.z;
    pl[5] = ox * u1.y + oy * u2.w;
#pragma unroll
    for (int off = 1; off < 64; off <<= 1) {
#pragma unroll
        for (int c = 0; c < 6; ++c) {
            pi[c] += __shfl_xor(pi[c], off);
            pl[c] += __shfl_xor(pl[c], off);
        }
    }
#pragma unroll
    for (int c = 0; c < 6; ++c) {
        pi[c] += bi[c];
        pl[c] += bl[c];
    }
    float mi = fmaxf(fmaxf(fmaxf(pi[0], pi[1]), fmaxf(pi[2], pi[3])), fmaxf(pi[4], pi[5]));
    float ml = fmaxf(fmaxf(fmaxf(pl[0], pl[1]), fmaxf(pl[2], pl[3])), fmaxf(pl[4], pl[5]));
    float si = 0.f, sl = 0.f;
#pragma unroll
    for (int c = 0; c < 6; ++c) {
        si += expf(pi[c] - mi);
        sl += expf(pl[c] - ml);
    }
    float lsi = mi + logf(si), lsl = ml + logf(sl);
#pragma unroll
    for (int c = 0; c < 6; ++c) {
        if (l == c)     out[(size_t)i * NC + c] = pi[c] - lsi;
        if (l == 6 + c) out[(size_t)NN * NC + (size_t)i * NC + c] = pl[c] - lsl;
    }
}

extern "C" void kernel_launch(void* const* d_in, const int* in_sizes, int n_in,
                              void* d_out, int out_size, void* d_ws, size_t ws_size,
                              hipStream_t stream) {
    const float* x  = (const float*)d_in[0];
    const int*   ei = (const int*)d_in[1];
    const float* W1 = (const float*)d_in[2];
    const float* b1 = (const float*)d_in[3];
    const float* W2 = (const float*)d_in[4];
    const float* b2 = (const float*)d_in[5];
    const float* Wi = (const float*)d_in[6];
    const float* bi = (const float*)d_in[7];
    const float* Wl = (const float*)d_in[8];
    const float* bl = (const float*)d_in[9];
    float* out = (float*)d_out;

    uint8_t* p = (uint8_t*)d_ws;
    auto alloc = [&](size_t bytes) {
        void* r = (void*)p;
        p += (bytes + 255) / 256 * 256;
        return r;
    };
    int* row_ptr = (int*)alloc((NN + 1) * sizeof(int));
    int* cursor  = (int*)alloc(NN * sizeof(int));
    int* col     = (int*)alloc(NE * sizeof(int));
    int* bsum    = (int*)alloc(64 * sizeof(int));
    float* dinv  = (float*)alloc(NN * sizeof(float));
    ushort* WT1p = (ushort*)alloc((size_t)KD * HIDD * sizeof(ushort));
    ushort* WT2p = (ushort*)alloc((size_t)HIDD * HIDD * sizeof(ushort));
    ushort* bufA = (ushort*)alloc((size_t)NN * HIDD * sizeof(ushort));
    ushort* bufB = (ushort*)alloc((size_t)NN * HIDD * sizeof(ushort));

    const int CB = NE / 256;   // 3125
    const int PB = 56;         // pack blocks

    hipMemsetAsync(cursor, 0, NN * sizeof(int), stream);
    count_prep_kernel<<<CB + PB, 256, 0, stream>>>(ei, cursor, W1, W2, WT1p, WT2p);
    scan_blocks_kernel<<<49, 256, 0, stream>>>(cursor, row_ptr, dinv, bsum);
    scan_add_kernel<<<(NN + 255) / 256, 256, 0, stream>>>(row_ptr, cursor, bsum);
    fill_kernel<<<CB, 256, 0, stream>>>(ei, cursor, col);

    const int grid = (NN + 63) / 64;   // 782
    // layer 1: hs1 = bf16(dinv*(x@W1)) ; h1 = bf16(relu(dinv*gather + b1))
    mfma_gemm1<<<grid, 256, 0, stream>>>(x, WT1p, dinv, bufA, NN);
    agg1_kernel<<<NN / 4, 256, 0, stream>>>(bufA, row_ptr, col, dinv, b1, bufB);
    // layer 2: hs2 = bf16(dinv*(h1@W2)) ; fused agg2 + heads
    mfma_gemm2<<<grid, 256, 0, stream>>>(bufB, WT2p, dinv, bufA, NN);
    agg2_heads_kernel<<<NN / 4, 256, 0, stream>>>(bufA, row_ptr, col, dinv, b2,
                                                  Wi, bi, Wl, bl, out);
}